// Round 10
// baseline (1530.318 us; speedup 1.0000x reference)
//
#include <hip/hip_runtime.h>
#include <hip/hip_bf16.h>
#include <hip/hip_fp16.h>
#include <math.h>

#define NN 100000
#define NE 1600000
#define INF_ 16
#define HF 64
#define NH 3
#define HID 192
#define NC 6
#define NEG_SLOPE 0.01f

#define BSH 9                 // bucket = dst >> 9 (512 nodes/bucket)
#define NBUCK 196             // ceil(100000/512)
#define TILE 2048

typedef _Float16 half8 __attribute__((ext_vector_type(8)));
typedef float f32x4 __attribute__((ext_vector_type(4)));

// ---------------- CSR build (bucketed) ----------------

__global__ __launch_bounds__(256) void k_bhist(const int* __restrict__ dst, int* __restrict__ bcnt) {
    __shared__ int c[NBUCK];
    int tid = threadIdx.x;
    for (int i = tid; i < NBUCK; i += 256) c[i] = 0;
    __syncthreads();
    int e0 = blockIdx.x * TILE;
    int end = min(e0 + TILE, NE);
    for (int i = e0 + tid; i < end; i += 256) atomicAdd(&c[dst[i] >> BSH], 1);
    __syncthreads();
    for (int i = tid; i < NBUCK; i += 256)
        if (c[i]) atomicAdd(&bcnt[i], c[i]);
}

__global__ __launch_bounds__(256) void k_bscan(const int* __restrict__ bcnt, int* __restrict__ bbase,
                                               int* __restrict__ gcur) {
    __shared__ int sc[256];
    int t = threadIdx.x;
    int v = (t < NBUCK) ? bcnt[t] : 0;
    sc[t] = v; __syncthreads();
    for (int off = 1; off < 256; off <<= 1) {
        int x = (t >= off) ? sc[t - off] : 0;
        __syncthreads();
        sc[t] += x;
        __syncthreads();
    }
    if (t < NBUCK) {
        bbase[t] = sc[t] - v;
        gcur[t] = sc[t] - v;
    }
    if (t == NBUCK - 1) bbase[NBUCK] = sc[t];   // == NE
}

__global__ __launch_bounds__(256) void k_bucket(const int* __restrict__ src, const int* __restrict__ dst,
                                                int* __restrict__ gcur, int* __restrict__ staged) {
    __shared__ int cnt[NBUCK], base[NBUCK], cnt2[NBUCK];
    int tid = threadIdx.x;
    int e0 = blockIdx.x * TILE;
    int cntE = min(TILE, NE - e0);
    for (int i = tid; i < NBUCK; i += 256) { cnt[i] = 0; cnt2[i] = 0; }
    __syncthreads();
    int myDst[8], mySrc[8];
#pragma unroll
    for (int k = 0; k < 8; ++k) {
        int idx = tid + k * 256;
        if (idx < cntE) {
            myDst[k] = dst[e0 + idx];
            mySrc[k] = src[e0 + idx];
            atomicAdd(&cnt[myDst[k] >> BSH], 1);
        }
    }
    __syncthreads();
    for (int i = tid; i < NBUCK; i += 256) {
        if (cnt[i] > 0) base[i] = atomicAdd(&gcur[i], cnt[i]);
    }
    __syncthreads();
#pragma unroll
    for (int k = 0; k < 8; ++k) {
        int idx = tid + k * 256;
        if (idx < cntE) {
            int b = myDst[k] >> BSH;
            int r = atomicAdd(&cnt2[b], 1);
            staged[base[b] + r] = ((myDst[k] & 511) << 17) | mySrc[k];
        }
    }
}

__global__ __launch_bounds__(256) void k_bscatter(const int* __restrict__ bbase, const int* __restrict__ staged,
                                                  int* __restrict__ colb, int* __restrict__ row_ptr) {
    __shared__ int cnt[512];
    __shared__ int cur[512];
    __shared__ int ssum[256];
    int b = blockIdx.x;
    int tid = threadIdx.x;
    int beg = bbase[b];
    int end = bbase[b + 1];
    cnt[2 * tid] = 0; cnt[2 * tid + 1] = 0;
    __syncthreads();
    for (int i = beg + tid; i < end; i += 256) atomicAdd(&cnt[staged[i] >> 17], 1);
    __syncthreads();
    int a0 = cnt[2 * tid], a1 = cnt[2 * tid + 1];
    ssum[tid] = a0 + a1;
    __syncthreads();
    for (int off = 1; off < 256; off <<= 1) {
        int x = (tid >= off) ? ssum[tid - off] : 0;
        __syncthreads();
        ssum[tid] += x;
        __syncthreads();
    }
    int ex = (tid ? ssum[tid - 1] : 0);
    int c0 = beg + ex;
    int c1 = beg + ex + a0;
    cur[2 * tid] = c0;
    cur[2 * tid + 1] = c1;
    int n0 = b << BSH;
    if (n0 + 2 * tid < NN) row_ptr[n0 + 2 * tid] = c0;
    if (n0 + 2 * tid + 1 < NN) row_ptr[n0 + 2 * tid + 1] = c1;
    if (b == NBUCK - 1 && tid == 0) row_ptr[NN] = end;   // == NE
    __syncthreads();
    for (int i = beg + tid; i < end; i += 256) {
        int v = staged[i];
        int pos = atomicAdd(&cur[v >> 17], 1);
        colb[pos] = (v & 0x1FFFF) * 384;
    }
}

// ---------------- degree counting-sort (descending) -> order[] ----------------

__global__ __launch_bounds__(256) void k_dhist(const int* __restrict__ row_ptr, int* __restrict__ dh) {
    __shared__ int c[256];
    int tid = threadIdx.x;
    c[tid] = 0;
    __syncthreads();
    int n = blockIdx.x * 256 + tid;
    if (n < NN) {
        int d = row_ptr[n + 1] - row_ptr[n];
        atomicAdd(&c[min(d, 255)], 1);
    }
    __syncthreads();
    if (c[tid]) atomicAdd(&dh[tid], c[tid]);
}

__global__ __launch_bounds__(256) void k_dscan(const int* __restrict__ dh, int* __restrict__ dcur) {
    __shared__ int sc[256];
    int t = threadIdx.x;
    int rb = 255 - t;          // reversed -> descending-degree base
    int v = dh[rb];
    sc[t] = v; __syncthreads();
    for (int off = 1; off < 256; off <<= 1) {
        int x = (t >= off) ? sc[t - off] : 0;
        __syncthreads();
        sc[t] += x;
        __syncthreads();
    }
    dcur[rb] = sc[t] - v;      // exclusive prefix
}

__global__ __launch_bounds__(256) void k_dscatter(const int* __restrict__ row_ptr, int* __restrict__ dcur,
                                                  int* __restrict__ order) {
    int n = blockIdx.x * 256 + threadIdx.x;
    if (n < NN) {
        int d = row_ptr[n + 1] - row_ptr[n];
        int pos = atomicAdd(&dcur[min(d, 255)], 1);
        order[pos] = n;
    }
}

// ---------------- W fp32 -> fp16 ----------------

__global__ __launch_bounds__(256) void k_cvtW(const float* __restrict__ W, __half* __restrict__ Wh, int n) {
    int i = blockIdx.x * 256 + threadIdx.x;
    if (i < n) Wh[i] = __float2half(W[i]);
}

// ---------------- prep: v = W^T a per layer ----------------

__global__ __launch_bounds__(256) void k_prep(const float* __restrict__ W1, const float* __restrict__ a1,
                                              const float* __restrict__ W, const float* __restrict__ a,
                                              float* __restrict__ v0, __half* __restrict__ vh) {
    int bid = blockIdx.x, tid = threadIdx.x;
    if (bid == 0) {
        if (tid < 96) {
            int j = tid >> 4, k = tid & 15;
            int h = j % 3, sd = j / 3;
            float s = 0.f;
            for (int c = 0; c < 64; ++c)
                s += W1[h * 1024 + c * 16 + k] * a1[h * 128 + sd * 64 + c];
            v0[j * 16 + k] = s;
        }
    } else {
        int l = bid - 1;
        if (tid < HID) {
            int k = tid;
            __half* vt = vh + (size_t)l * 16 * HID;
            for (int j = 0; j < 6; ++j) {
                int h = j % 3, sd = j / 3;
                const float* wp = W + (size_t)l * 36864 + h * 12288 + k;
                const float* ap = a + (size_t)l * 384 + h * 128 + sd * 64;
                float s = 0.f;
                for (int c = 0; c < 64; ++c) s += wp[c * 192] * ap[c];
                __half hi = __float2half(s);
                __half lo = __float2half(s - __half2float(hi));
                vt[j * HID + k] = hi;
                vt[(j + 6) * HID + k] = lo;
            }
            for (int j = 12; j < 16; ++j) vt[j * HID + k] = __float2half(0.f);
        }
    }
}

// ---------------- layer 1 transform: thread = 4 nodes x 8 cols ----------------

__global__ __launch_bounds__(256) void k_transform1(const float* __restrict__ feat, const float* __restrict__ W1,
                                                    __half* __restrict__ zh) {
    int idx = blockIdx.x * 256 + threadIdx.x;
    if (idx >= (NN / 4) * 24) return;
    int n4 = idx / 24;
    int seg = idx - n4 * 24;      // 0..23: cols seg*8..+8
    int nbase = n4 * 4;
    const float* wr = W1 + seg * 8 * INF_;

    float acc[4][8];
#pragma unroll
    for (int j = 0; j < 4; ++j)
#pragma unroll
        for (int r = 0; r < 8; ++r) acc[j][r] = 0.f;

#pragma unroll
    for (int k4 = 0; k4 < 4; ++k4) {
        float4 f[4], w[8];
#pragma unroll
        for (int j = 0; j < 4; ++j) f[j] = *(const float4*)&feat[(nbase + j) * INF_ + k4 * 4];
#pragma unroll
        for (int r = 0; r < 8; ++r) w[r] = *(const float4*)&wr[r * INF_ + k4 * 4];
#pragma unroll
        for (int j = 0; j < 4; ++j)
#pragma unroll
            for (int r = 0; r < 8; ++r)
                acc[j][r] += f[j].x * w[r].x + f[j].y * w[r].y + f[j].z * w[r].z + f[j].w * w[r].w;
    }
#pragma unroll
    for (int j = 0; j < 4; ++j) {
        half8 o;
#pragma unroll
        for (int r = 0; r < 8; ++r) o[r] = (_Float16)acc[j][r];
        *(half8*)&zh[(size_t)(nbase + j) * HID + seg * 8] = o;
    }
}

// ---------------- layer 1 es/ed ----------------

__global__ __launch_bounds__(256) void k_esed1(const float* __restrict__ feat, const float* __restrict__ v0,
                                               float* __restrict__ es, float* __restrict__ ed) {
    __shared__ float sv[96];
    int tid = threadIdx.x;
    if (tid < 96) sv[tid] = v0[tid];
    __syncthreads();
    int n = blockIdx.x * 256 + tid;
    if (n >= NN) return;
    float f[16];
#pragma unroll
    for (int i = 0; i < 16; i += 4) {
        float4 t4 = *(const float4*)&feat[n * 16 + i];
        f[i] = t4.x; f[i + 1] = t4.y; f[i + 2] = t4.z; f[i + 3] = t4.w;
    }
#pragma unroll
    for (int j = 0; j < 6; ++j) {
        float s = 0.f;
#pragma unroll
        for (int k = 0; k < 16; ++k) s += f[k] * sv[j * 16 + k];
        if (j < 3) es[n * 3 + j] = s;
        else ed[n * 3 + (j - 3)] = s;
    }
}

// ---------------- layers 2..8 transform via MFMA, LDS-staged B, fused es/ed ----------------

__global__ __launch_bounds__(256) void k_mfma(const __half* __restrict__ Ah, const __half* __restrict__ Whl,
                                              const __half* __restrict__ vhl,
                                              __half* __restrict__ zh, float* __restrict__ es,
                                              float* __restrict__ ed) {
    __shared__ char Bs[73728];
    int tid = threadIdx.x;

#pragma unroll
    for (int i = 0; i < 18; ++i) {
        int idx = tid + i * 256;
        int row = idx / 24;
        int pos = idx - row * 24;
        uint4 v = *(const uint4*)((const char*)Whl + (size_t)idx * 16);
        *(uint4*)(Bs + row * 384 + ((pos * 16) ^ ((row & 7) << 4))) = v;
    }
    __syncthreads();

    int wid = tid >> 6;
    int lane = tid & 63;
    int lrow = lane & 15;
    int lk = lane >> 4;  // 0..3
    int r0 = blockIdx.x * 128 + wid * 32;

    int arow0 = min(r0 + lrow, NN - 1);
    int arow1 = min(r0 + 16 + lrow, NN - 1);
    const __half* ap0 = &Ah[(size_t)arow0 * HID];
    const __half* ap1 = &Ah[(size_t)arow1 * HID];

    f32x4 acc[2][12];
    f32x4 acc13[2];
#pragma unroll
    for (int f = 0; f < 2; ++f) {
        acc13[f] = (f32x4){0.f, 0.f, 0.f, 0.f};
#pragma unroll
        for (int t = 0; t < 12; ++t) acc[f][t] = (f32x4){0.f, 0.f, 0.f, 0.f};
    }

#pragma unroll
    for (int ks = 0; ks < 6; ++ks) {
        half8 a0 = *(const half8*)&ap0[ks * 32 + lk * 8];
        half8 a1 = *(const half8*)&ap1[ks * 32 + lk * 8];
        half8 b13 = *(const half8*)&vhl[lrow * HID + ks * 32 + lk * 8];
        acc13[0] = __builtin_amdgcn_mfma_f32_16x16x32_f16(a0, b13, acc13[0], 0, 0, 0);
        acc13[1] = __builtin_amdgcn_mfma_f32_16x16x32_f16(a1, b13, acc13[1], 0, 0, 0);
#pragma unroll
        for (int t = 0; t < 12; ++t) {
            int brow = t * 16 + lrow;
            half8 bf = *(const half8*)(Bs + brow * 384 + ((ks * 64 + lk * 16) ^ ((brow & 7) << 4)));
            acc[0][t] = __builtin_amdgcn_mfma_f32_16x16x32_f16(a0, bf, acc[0][t], 0, 0, 0);
            acc[1][t] = __builtin_amdgcn_mfma_f32_16x16x32_f16(a1, bf, acc[1][t], 0, 0, 0);
        }
    }

#pragma unroll
    for (int f = 0; f < 2; ++f) {
        int orow0 = r0 + f * 16 + lk * 4;
#pragma unroll
        for (int t = 0; t < 12; ++t) {
#pragma unroll
            for (int g = 0; g < 4; ++g) {
                int row = orow0 + g;
                if (row < NN) zh[(size_t)row * HID + t * 16 + lrow] = __float2half(acc[f][t][g]);
            }
        }
#pragma unroll
        for (int g = 0; g < 4; ++g) {
            float vhi = acc13[f][g];
            float vlo = __shfl(vhi, lane + 6);
            float tot = vhi + vlo;
            int row = orow0 + g;
            if (row < NN) {
                if (lrow < 3) es[row * NH + lrow] = tot;
                else if (lrow < 6) ed[row * NH + (lrow - 3)] = tot;
            }
        }
    }
}

// ---------------- aggregate: wave = 2 nodes x 32 lanes (24 active), degree-sorted order ----------------

__global__ __launch_bounds__(256) void k_agg(const __half* __restrict__ zh, const int* __restrict__ colb,
                                             const float* __restrict__ es, const float* __restrict__ ed,
                                             const int* __restrict__ row_ptr, const int* __restrict__ order,
                                             __half* __restrict__ h_out) {
    int w = blockIdx.x * 4 + (threadIdx.x >> 6);      // wave id: 0..NN/2-1
    int lane = threadIdx.x & 63;
    int slot = lane >> 5;
    int sub = lane & 31;          // 0..31; active for z if sub < 24
    int n = order[w * 2 + slot];
    int beg = row_ptr[n];
    int deg = row_ptr[n + 1] - beg;
    int head = sub >> 3;          // 0..2 for active lanes
    bool act = sub < 24;

    float3 d3 = *(const float3*)((const char*)ed + n * 12);
    float dv = (head == 0) ? d3.x : (head == 1) ? d3.y : d3.z;

    const int* cp = colb + beg;
    const char* zb = (const char*)zh + sub * 16;

    float l = 0.f;
    float acc[8];
#pragma unroll
    for (int k = 0; k < 8; ++k) acc[k] = 0.f;

    int so_n = 0;
    float3 s3_n = make_float3(0.f, 0.f, 0.f);
    if (deg > 0) { so_n = cp[0]; s3_n = *(const float3*)((const char*)es + (so_n >> 5)); }

    for (int i = 0; i < deg; ++i) {
        int so = so_n;
        float3 s3 = s3_n;
        if (i + 1 < deg) { so_n = cp[i + 1]; s3_n = *(const float3*)((const char*)es + (so_n >> 5)); }
        float sv = (head == 0) ? s3.x : (head == 1) ? s3.y : s3.z;
        float x = sv + dv;
        x = fmaxf(x, NEG_SLOPE * x);
        float p = __expf(x);
        l += p;
        if (act) {
            half8 z = *(const half8*)(zb + so);
#pragma unroll
            for (int k = 0; k < 8; ++k) acc[k] += p * (float)z[k];
        }
    }

    if (act) {
        float rl = 1.f / fmaxf(l, 1e-9f);
        union { float4 f4; __half2 h2[4]; } u;
#pragma unroll
        for (int k = 0; k < 4; ++k) {
            float x0 = acc[2 * k] * rl, x1 = acc[2 * k + 1] * rl;
            x0 = (x0 > 0.f) ? x0 : (__expf(x0) - 1.f);   // ELU
            x1 = (x1 > 0.f) ? x1 : (__expf(x1) - 1.f);
            u.h2[k] = __floats2half2_rn(x0, x1);
        }
        *(float4*)((char*)h_out + (size_t)n * 384 + sub * 16) = u.f4;
    }
}

// ---------------- final FC (fp16 h in) ----------------

__device__ inline float wred_sum(float v) {
#pragma unroll
    for (int o = 32; o; o >>= 1) v += __shfl_xor(v, o);
    return v;
}

__global__ __launch_bounds__(256) void k_fc(const __half* __restrict__ hbuf, const float* __restrict__ fcW,
                                            const float* __restrict__ fcb, float* __restrict__ out) {
    __shared__ float sW[NC * HID];
    __shared__ float sb[NC];
    int tid = threadIdx.x;
    for (int i = tid; i < NC * HID; i += 256) sW[i] = fcW[i];
    if (tid < NC) sb[tid] = fcb[tid];
    __syncthreads();
    int w = tid >> 6;
    int lane = tid & 63;
    int n = blockIdx.x * 4 + w;
    if (n >= NN) return;
    float h0 = __half2float(hbuf[(size_t)n * HID + lane]);
    float h1 = __half2float(hbuf[(size_t)n * HID + 64 + lane]);
    float h2 = __half2float(hbuf[(size_t)n * HID + 128 + lane]);
#pragma unroll
    for (int j = 0; j < NC; ++j) {
        float p = h0 * sW[j * HID + lane] + h1 * sW[j * HID + 64 + lane] + h2 * sW[j * HID + 128 + lane];
        p = wred_sum(p);
        if (lane == 0) out[n * NC + j] = p + sb[j];
    }
}

// ---------------- host ----------------

extern "C" void kernel_launch(void* const* d_in, const int* in_sizes, int n_in,
                              void* d_out, int out_size, void* d_ws, size_t ws_size,
                              hipStream_t stream) {
    const float* node_feat = (const float*)d_in[0];
    const int* src = (const int*)d_in[1];
    const int* dst = (const int*)d_in[2];
    const float* W1 = (const float*)d_in[3];   // [3,64,16]
    const float* a1 = (const float*)d_in[4];   // [3,128]
    const float* W = (const float*)d_in[5];    // [7,3,64,192]
    const float* a = (const float*)d_in[6];    // [7,3,128]
    const float* fcW = (const float*)d_in[7];  // [6,192]
    const float* fcb = (const float*)d_in[8];  // [6]
    float* out = (float*)d_out;

    char* p = (char*)d_ws;
    auto alloc = [&](size_t bytes) {
        void* r = (void*)p;
        p += (bytes + 255) & ~(size_t)255;
        return r;
    };
    int* row_ptr = (int*)alloc((NN + 1) * 4);
    int* bcnt = (int*)alloc(NBUCK * 4);
    int* bbase = (int*)alloc((NBUCK + 1) * 4);
    int* gcur = (int*)alloc(NBUCK * 4);
    int* dh = (int*)alloc(256 * 4);
    int* dcur = (int*)alloc(256 * 4);
    int* order = (int*)alloc((size_t)NN * 4);
    int* staged = (int*)alloc((size_t)NE * 4);
    int* colb = (int*)alloc((size_t)NE * 4);
    float* es = (float*)alloc((size_t)NN * NH * 4);
    float* ed = (float*)alloc((size_t)NN * NH * 4);
    __half* zh = (__half*)alloc((size_t)NN * HID * 2);
    __half* hb = (__half*)alloc((size_t)NN * HID * 2);
    const int NWH = 7 * NH * HF * HID;  // 258048
    __half* Wh = (__half*)alloc((size_t)NWH * 2);
    float* v0 = (float*)alloc(96 * 4);
    __half* vh = (__half*)alloc((size_t)7 * 16 * HID * 2);

    int nb = (NN + 255) / 256;          // 391
    int gTile = (NE + TILE - 1) / TILE; // 782

    hipMemsetAsync(bcnt, 0, NBUCK * 4, stream);
    hipMemsetAsync(dh, 0, 256 * 4, stream);
    k_bhist<<<gTile, 256, 0, stream>>>(dst, bcnt);
    k_bscan<<<1, 256, 0, stream>>>(bcnt, bbase, gcur);
    k_bucket<<<gTile, 256, 0, stream>>>(src, dst, gcur, staged);
    k_bscatter<<<NBUCK, 256, 0, stream>>>(bbase, staged, colb, row_ptr);
    k_dhist<<<nb, 256, 0, stream>>>(row_ptr, dh);
    k_dscan<<<1, 256, 0, stream>>>(dh, dcur);
    k_dscatter<<<nb, 256, 0, stream>>>(row_ptr, dcur, order);
    k_cvtW<<<(NWH + 255) / 256, 256, 0, stream>>>(W, Wh, NWH);
    k_prep<<<8, 256, 0, stream>>>(W1, a1, W, a, v0, vh);

    int gAgg = NN / 2 / 4;              // 12500 blocks (NN/2 waves), exact
    int gT1 = ((NN / 4) * 24 + 255) / 256;  // 2344

    // layer 1
    k_transform1<<<gT1, 256, 0, stream>>>(node_feat, W1, zh);
    k_esed1<<<nb, 256, 0, stream>>>(node_feat, v0, es, ed);
    k_agg<<<gAgg, 256, 0, stream>>>(zh, colb, es, ed, row_ptr, order, hb);

    // layers 2..8
    for (int l = 0; l < 7; ++l) {
        k_mfma<<<(NN + 127) / 128, 256, 0, stream>>>(hb, Wh + (size_t)l * NH * HF * HID,
                                                     vh + (size_t)l * 16 * HID, zh, es, ed);
        k_agg<<<gAgg, 256, 0, stream>>>(zh, colb, es, ed, row_ptr, order, hb);
    }

    k_fc<<<(NN + 3) / 4, 256, 0, stream>>>(hb, fcW, fcb, out);
}

// Round 11
// 1425.674 us; speedup vs baseline: 1.0734x; 1.0734x over previous
//
#include <hip/hip_runtime.h>
#include <hip/hip_bf16.h>
#include <hip/hip_fp16.h>
#include <math.h>

#define NN 100000
#define NE 1600000
#define INF_ 16
#define HF 64
#define NH 3
#define HID 192
#define NC 6
#define NEG_SLOPE 0.01f

#define BSH 9                 // bucket = dst >> 9 (512 nodes/bucket)
#define NBUCK 196             // ceil(100000/512)
#define TILE 2048

typedef _Float16 half8 __attribute__((ext_vector_type(8)));
typedef float f32x4 __attribute__((ext_vector_type(4)));

// ---------------- CSR build (bucketed) ----------------

__global__ __launch_bounds__(256) void k_bhist(const int* __restrict__ dst, int* __restrict__ bcnt) {
    __shared__ int c[NBUCK];
    int tid = threadIdx.x;
    for (int i = tid; i < NBUCK; i += 256) c[i] = 0;
    __syncthreads();
    int e0 = blockIdx.x * TILE;
    int end = min(e0 + TILE, NE);
    for (int i = e0 + tid; i < end; i += 256) atomicAdd(&c[dst[i] >> BSH], 1);
    __syncthreads();
    for (int i = tid; i < NBUCK; i += 256)
        if (c[i]) atomicAdd(&bcnt[i], c[i]);
}

__global__ __launch_bounds__(256) void k_bscan(const int* __restrict__ bcnt, int* __restrict__ bbase,
                                               int* __restrict__ gcur) {
    __shared__ int sc[256];
    int t = threadIdx.x;
    int v = (t < NBUCK) ? bcnt[t] : 0;
    sc[t] = v; __syncthreads();
    for (int off = 1; off < 256; off <<= 1) {
        int x = (t >= off) ? sc[t - off] : 0;
        __syncthreads();
        sc[t] += x;
        __syncthreads();
    }
    if (t < NBUCK) {
        bbase[t] = sc[t] - v;
        gcur[t] = sc[t] - v;
    }
    if (t == NBUCK - 1) bbase[NBUCK] = sc[t];   // == NE
}

__global__ __launch_bounds__(256) void k_bucket(const int* __restrict__ src, const int* __restrict__ dst,
                                                int* __restrict__ gcur, int* __restrict__ staged) {
    __shared__ int cnt[NBUCK], base[NBUCK], cnt2[NBUCK];
    int tid = threadIdx.x;
    int e0 = blockIdx.x * TILE;
    int cntE = min(TILE, NE - e0);
    for (int i = tid; i < NBUCK; i += 256) { cnt[i] = 0; cnt2[i] = 0; }
    __syncthreads();
    int myDst[8], mySrc[8];
#pragma unroll
    for (int k = 0; k < 8; ++k) {
        int idx = tid + k * 256;
        if (idx < cntE) {
            myDst[k] = dst[e0 + idx];
            mySrc[k] = src[e0 + idx];
            atomicAdd(&cnt[myDst[k] >> BSH], 1);
        }
    }
    __syncthreads();
    for (int i = tid; i < NBUCK; i += 256) {
        if (cnt[i] > 0) base[i] = atomicAdd(&gcur[i], cnt[i]);
    }
    __syncthreads();
#pragma unroll
    for (int k = 0; k < 8; ++k) {
        int idx = tid + k * 256;
        if (idx < cntE) {
            int b = myDst[k] >> BSH;
            int r = atomicAdd(&cnt2[b], 1);
            staged[base[b] + r] = ((myDst[k] & 511) << 17) | mySrc[k];
        }
    }
}

__global__ __launch_bounds__(256) void k_bscatter(const int* __restrict__ bbase, const int* __restrict__ staged,
                                                  int* __restrict__ colb, int* __restrict__ row_ptr) {
    __shared__ int cnt[512];
    __shared__ int cur[512];
    __shared__ int ssum[256];
    int b = blockIdx.x;
    int tid = threadIdx.x;
    int beg = bbase[b];
    int end = bbase[b + 1];
    cnt[2 * tid] = 0; cnt[2 * tid + 1] = 0;
    __syncthreads();
    for (int i = beg + tid; i < end; i += 256) atomicAdd(&cnt[staged[i] >> 17], 1);
    __syncthreads();
    int a0 = cnt[2 * tid], a1 = cnt[2 * tid + 1];
    ssum[tid] = a0 + a1;
    __syncthreads();
    for (int off = 1; off < 256; off <<= 1) {
        int x = (tid >= off) ? ssum[tid - off] : 0;
        __syncthreads();
        ssum[tid] += x;
        __syncthreads();
    }
    int ex = (tid ? ssum[tid - 1] : 0);
    int c0 = beg + ex;
    int c1 = beg + ex + a0;
    cur[2 * tid] = c0;
    cur[2 * tid + 1] = c1;
    int n0 = b << BSH;
    if (n0 + 2 * tid < NN) row_ptr[n0 + 2 * tid] = c0;
    if (n0 + 2 * tid + 1 < NN) row_ptr[n0 + 2 * tid + 1] = c1;
    if (b == NBUCK - 1 && tid == 0) row_ptr[NN] = end;   // == NE
    __syncthreads();
    for (int i = beg + tid; i < end; i += 256) {
        int v = staged[i];
        int pos = atomicAdd(&cur[v >> 17], 1);
        colb[pos] = (v & 0x1FFFF) * 384;
    }
}

// ---------------- W fp32 -> fp16 ----------------

__global__ __launch_bounds__(256) void k_cvtW(const float* __restrict__ W, __half* __restrict__ Wh, int n) {
    int i = blockIdx.x * 256 + threadIdx.x;
    if (i < n) Wh[i] = __float2half(W[i]);
}

// ---------------- prep: v = W^T a per layer ----------------

__global__ __launch_bounds__(256) void k_prep(const float* __restrict__ W1, const float* __restrict__ a1,
                                              const float* __restrict__ W, const float* __restrict__ a,
                                              float* __restrict__ v0, __half* __restrict__ vh) {
    int bid = blockIdx.x, tid = threadIdx.x;
    if (bid == 0) {
        if (tid < 96) {
            int j = tid >> 4, k = tid & 15;
            int h = j % 3, sd = j / 3;
            float s = 0.f;
            for (int c = 0; c < 64; ++c)
                s += W1[h * 1024 + c * 16 + k] * a1[h * 128 + sd * 64 + c];
            v0[j * 16 + k] = s;
        }
    } else {
        int l = bid - 1;
        if (tid < HID) {
            int k = tid;
            __half* vt = vh + (size_t)l * 16 * HID;
            for (int j = 0; j < 6; ++j) {
                int h = j % 3, sd = j / 3;
                const float* wp = W + (size_t)l * 36864 + h * 12288 + k;
                const float* ap = a + (size_t)l * 384 + h * 128 + sd * 64;
                float s = 0.f;
                for (int c = 0; c < 64; ++c) s += wp[c * 192] * ap[c];
                __half hi = __float2half(s);
                __half lo = __float2half(s - __half2float(hi));
                vt[j * HID + k] = hi;
                vt[(j + 6) * HID + k] = lo;
            }
            for (int j = 12; j < 16; ++j) vt[j * HID + k] = __float2half(0.f);
        }
    }
}

// ---------------- layer 1 transform: thread = 4 nodes x 8 cols ----------------

__global__ __launch_bounds__(256) void k_transform1(const float* __restrict__ feat, const float* __restrict__ W1,
                                                    __half* __restrict__ zh) {
    int idx = blockIdx.x * 256 + threadIdx.x;
    if (idx >= (NN / 4) * 24) return;
    int n4 = idx / 24;
    int seg = idx - n4 * 24;      // 0..23: cols seg*8..+8
    int nbase = n4 * 4;
    const float* wr = W1 + seg * 8 * INF_;

    float acc[4][8];
#pragma unroll
    for (int j = 0; j < 4; ++j)
#pragma unroll
        for (int r = 0; r < 8; ++r) acc[j][r] = 0.f;

#pragma unroll
    for (int k4 = 0; k4 < 4; ++k4) {
        float4 f[4], w[8];
#pragma unroll
        for (int j = 0; j < 4; ++j) f[j] = *(const float4*)&feat[(nbase + j) * INF_ + k4 * 4];
#pragma unroll
        for (int r = 0; r < 8; ++r) w[r] = *(const float4*)&wr[r * INF_ + k4 * 4];
#pragma unroll
        for (int j = 0; j < 4; ++j)
#pragma unroll
            for (int r = 0; r < 8; ++r)
                acc[j][r] += f[j].x * w[r].x + f[j].y * w[r].y + f[j].z * w[r].z + f[j].w * w[r].w;
    }
#pragma unroll
    for (int j = 0; j < 4; ++j) {
        half8 o;
#pragma unroll
        for (int r = 0; r < 8; ++r) o[r] = (_Float16)acc[j][r];
        *(half8*)&zh[(size_t)(nbase + j) * HID + seg * 8] = o;
    }
}

// ---------------- layer 1 es/ed ----------------

__global__ __launch_bounds__(256) void k_esed1(const float* __restrict__ feat, const float* __restrict__ v0,
                                               float* __restrict__ es, float* __restrict__ ed) {
    __shared__ float sv[96];
    int tid = threadIdx.x;
    if (tid < 96) sv[tid] = v0[tid];
    __syncthreads();
    int n = blockIdx.x * 256 + tid;
    if (n >= NN) return;
    float f[16];
#pragma unroll
    for (int i = 0; i < 16; i += 4) {
        float4 t4 = *(const float4*)&feat[n * 16 + i];
        f[i] = t4.x; f[i + 1] = t4.y; f[i + 2] = t4.z; f[i + 3] = t4.w;
    }
#pragma unroll
    for (int j = 0; j < 6; ++j) {
        float s = 0.f;
#pragma unroll
        for (int k = 0; k < 16; ++k) s += f[k] * sv[j * 16 + k];
        if (j < 3) es[n * 3 + j] = s;
        else ed[n * 3 + (j - 3)] = s;
    }
}

// ---------------- layers 2..8 transform via MFMA ----------------
// Bs LDS halved (36.9KB, K split in two stages) -> 4 blocks/CU, 16 waves/CU.
// swizzle: byte = row*192 + ((p ^ (row&3))<<4), p = ksl*4+lk in 0..11 (stays in-row).

__global__ __launch_bounds__(256) void k_mfma(const __half* __restrict__ Ah, const __half* __restrict__ Whl,
                                              const __half* __restrict__ vhl,
                                              __half* __restrict__ zh, float* __restrict__ es,
                                              float* __restrict__ ed) {
    __shared__ char Bs[36864];
    int tid = threadIdx.x;
    int wid = tid >> 6;
    int lane = tid & 63;
    int lrow = lane & 15;
    int lk = lane >> 4;  // 0..3
    int r0 = blockIdx.x * 128 + wid * 32;

    int arow0 = min(r0 + lrow, NN - 1);
    int arow1 = min(r0 + 16 + lrow, NN - 1);
    const __half* ap0 = &Ah[(size_t)arow0 * HID];
    const __half* ap1 = &Ah[(size_t)arow1 * HID];

    f32x4 acc[2][12];
    f32x4 acc13[2];
#pragma unroll
    for (int f = 0; f < 2; ++f) {
        acc13[f] = (f32x4){0.f, 0.f, 0.f, 0.f};
#pragma unroll
        for (int t = 0; t < 12; ++t) acc[f][t] = (f32x4){0.f, 0.f, 0.f, 0.f};
    }

#pragma unroll
    for (int hf = 0; hf < 2; ++hf) {
        // stage half of B: 192 rows x 192B (K-cols hf*96..+96); 2304 x 16B, 9/thread
#pragma unroll
        for (int i = 0; i < 9; ++i) {
            int idx = tid + i * 256;
            int row = idx / 12;
            int pp = idx - row * 12;
            uint4 v = *(const uint4*)((const char*)Whl + (size_t)row * 384 + hf * 192 + pp * 16);
            *(uint4*)(Bs + row * 192 + ((pp ^ (row & 3)) << 4)) = v;
        }
        __syncthreads();
#pragma unroll
        for (int ksl = 0; ksl < 3; ++ksl) {
            int ks = hf * 3 + ksl;
            half8 a0 = *(const half8*)&ap0[ks * 32 + lk * 8];
            half8 a1 = *(const half8*)&ap1[ks * 32 + lk * 8];
            half8 b13 = *(const half8*)&vhl[lrow * HID + ks * 32 + lk * 8];
            acc13[0] = __builtin_amdgcn_mfma_f32_16x16x32_f16(a0, b13, acc13[0], 0, 0, 0);
            acc13[1] = __builtin_amdgcn_mfma_f32_16x16x32_f16(a1, b13, acc13[1], 0, 0, 0);
            int p = ksl * 4 + lk;
#pragma unroll
            for (int t = 0; t < 12; ++t) {
                int brow = t * 16 + lrow;
                half8 bf = *(const half8*)(Bs + brow * 192 + ((p ^ (brow & 3)) << 4));
                acc[0][t] = __builtin_amdgcn_mfma_f32_16x16x32_f16(a0, bf, acc[0][t], 0, 0, 0);
                acc[1][t] = __builtin_amdgcn_mfma_f32_16x16x32_f16(a1, bf, acc[1][t], 0, 0, 0);
            }
        }
        __syncthreads();
    }

#pragma unroll
    for (int f = 0; f < 2; ++f) {
        int orow0 = r0 + f * 16 + lk * 4;
#pragma unroll
        for (int t = 0; t < 12; ++t) {
#pragma unroll
            for (int g = 0; g < 4; ++g) {
                int row = orow0 + g;
                if (row < NN) zh[(size_t)row * HID + t * 16 + lrow] = __float2half(acc[f][t][g]);
            }
        }
#pragma unroll
        for (int g = 0; g < 4; ++g) {
            float vhi = acc13[f][g];
            float vlo = __shfl(vhi, lane + 6);
            float tot = vhi + vlo;
            int row = orow0 + g;
            if (row < NN) {
                if (lrow < 3) es[row * NH + lrow] = tot;
                else if (lrow < 6) ed[row * NH + (lrow - 3)] = tot;
            }
        }
    }
}

// ---------------- aggregate: wave = 2 nodes x 32 lanes (24 active) ----------------

__global__ __launch_bounds__(256) void k_agg(const __half* __restrict__ zh, const int* __restrict__ colb,
                                             const float* __restrict__ es, const float* __restrict__ ed,
                                             const int* __restrict__ row_ptr, __half* __restrict__ h_out) {
    int w = blockIdx.x * 4 + (threadIdx.x >> 6);      // wave id: 0..NN/2-1
    int lane = threadIdx.x & 63;
    int slot = lane >> 5;
    int sub = lane & 31;          // 0..31; active for z if sub < 24
    int n = w * 2 + slot;
    int beg = row_ptr[n];
    int deg = row_ptr[n + 1] - beg;
    int head = sub >> 3;          // 0..2 for active lanes
    bool act = sub < 24;

    float3 d3 = *(const float3*)((const char*)ed + n * 12);
    float dv = (head == 0) ? d3.x : (head == 1) ? d3.y : d3.z;

    const int* cp = colb + beg;
    const char* zb = (const char*)zh + sub * 16;

    float l = 0.f;
    float acc[8];
#pragma unroll
    for (int k = 0; k < 8; ++k) acc[k] = 0.f;

    int so_n = 0;
    float3 s3_n = make_float3(0.f, 0.f, 0.f);
    if (deg > 0) { so_n = cp[0]; s3_n = *(const float3*)((const char*)es + (so_n >> 5)); }

    for (int i = 0; i < deg; ++i) {
        int so = so_n;
        float3 s3 = s3_n;
        if (i + 1 < deg) { so_n = cp[i + 1]; s3_n = *(const float3*)((const char*)es + (so_n >> 5)); }
        float sv = (head == 0) ? s3.x : (head == 1) ? s3.y : s3.z;
        float x = sv + dv;
        x = fmaxf(x, NEG_SLOPE * x);
        float p = __expf(x);
        l += p;
        if (act) {
            half8 z = *(const half8*)(zb + so);
#pragma unroll
            for (int k = 0; k < 8; ++k) acc[k] += p * (float)z[k];
        }
    }

    if (act) {
        float rl = 1.f / fmaxf(l, 1e-9f);
        union { float4 f4; __half2 h2[4]; } u;
#pragma unroll
        for (int k = 0; k < 4; ++k) {
            float x0 = acc[2 * k] * rl, x1 = acc[2 * k + 1] * rl;
            x0 = (x0 > 0.f) ? x0 : (__expf(x0) - 1.f);   // ELU
            x1 = (x1 > 0.f) ? x1 : (__expf(x1) - 1.f);
            u.h2[k] = __floats2half2_rn(x0, x1);
        }
        *(float4*)((char*)h_out + (size_t)n * 384 + sub * 16) = u.f4;
    }
}

// ---------------- final FC (fp16 h in) ----------------

__device__ inline float wred_sum(float v) {
#pragma unroll
    for (int o = 32; o; o >>= 1) v += __shfl_xor(v, o);
    return v;
}

__global__ __launch_bounds__(256) void k_fc(const __half* __restrict__ hbuf, const float* __restrict__ fcW,
                                            const float* __restrict__ fcb, float* __restrict__ out) {
    __shared__ float sW[NC * HID];
    __shared__ float sb[NC];
    int tid = threadIdx.x;
    for (int i = tid; i < NC * HID; i += 256) sW[i] = fcW[i];
    if (tid < NC) sb[tid] = fcb[tid];
    __syncthreads();
    int w = tid >> 6;
    int lane = tid & 63;
    int n = blockIdx.x * 4 + w;
    if (n >= NN) return;
    float h0 = __half2float(hbuf[(size_t)n * HID + lane]);
    float h1 = __half2float(hbuf[(size_t)n * HID + 64 + lane]);
    float h2 = __half2float(hbuf[(size_t)n * HID + 128 + lane]);
#pragma unroll
    for (int j = 0; j < NC; ++j) {
        float p = h0 * sW[j * HID + lane] + h1 * sW[j * HID + 64 + lane] + h2 * sW[j * HID + 128 + lane];
        p = wred_sum(p);
        if (lane == 0) out[n * NC + j] = p + sb[j];
    }
}

// ---------------- host ----------------

extern "C" void kernel_launch(void* const* d_in, const int* in_sizes, int n_in,
                              void* d_out, int out_size, void* d_ws, size_t ws_size,
                              hipStream_t stream) {
    const float* node_feat = (const float*)d_in[0];
    const int* src = (const int*)d_in[1];
    const int* dst = (const int*)d_in[2];
    const float* W1 = (const float*)d_in[3];   // [3,64,16]
    const float* a1 = (const float*)d_in[4];   // [3,128]
    const float* W = (const float*)d_in[5];    // [7,3,64,192]
    const float* a = (const float*)d_in[6];    // [7,3,128]
    const float* fcW = (const float*)d_in[7];  // [6,192]
    const float* fcb = (const float*)d_in[8];  // [6]
    float* out = (float*)d_out;

    char* p = (char*)d_ws;
    auto alloc = [&](size_t bytes) {
        void* r = (void*)p;
        p += (bytes + 255) & ~(size_t)255;
        return r;
    };
    int* row_ptr = (int*)alloc((NN + 1) * 4);
    int* bcnt = (int*)alloc(NBUCK * 4);
    int* bbase = (int*)alloc((NBUCK + 1) * 4);
    int* gcur = (int*)alloc(NBUCK * 4);
    int* staged = (int*)alloc((size_t)NE * 4);
    int* colb = (int*)alloc((size_t)NE * 4);
    float* es = (float*)alloc((size_t)NN * NH * 4);
    float* ed = (float*)alloc((size_t)NN * NH * 4);
    __half* zh = (__half*)alloc((size_t)NN * HID * 2);
    __half* hb = (__half*)alloc((size_t)NN * HID * 2);
    const int NWH = 7 * NH * HF * HID;  // 258048
    __half* Wh = (__half*)alloc((size_t)NWH * 2);
    float* v0 = (float*)alloc(96 * 4);
    __half* vh = (__half*)alloc((size_t)7 * 16 * HID * 2);

    int nb = (NN + 255) / 256;          // 391
    int gTile = (NE + TILE - 1) / TILE; // 782

    hipMemsetAsync(bcnt, 0, NBUCK * 4, stream);
    k_bhist<<<gTile, 256, 0, stream>>>(dst, bcnt);
    k_bscan<<<1, 256, 0, stream>>>(bcnt, bbase, gcur);
    k_bucket<<<gTile, 256, 0, stream>>>(src, dst, gcur, staged);
    k_bscatter<<<NBUCK, 256, 0, stream>>>(bbase, staged, colb, row_ptr);
    k_cvtW<<<(NWH + 255) / 256, 256, 0, stream>>>(W, Wh, NWH);
    k_prep<<<8, 256, 0, stream>>>(W1, a1, W, a, v0, vh);

    int gAgg = NN / 2 / 4;              // 12500 blocks (NN/2 waves), exact
    int gT1 = ((NN / 4) * 24 + 255) / 256;  // 2344

    // layer 1
    k_transform1<<<gT1, 256, 0, stream>>>(node_feat, W1, zh);
    k_esed1<<<nb, 256, 0, stream>>>(node_feat, v0, es, ed);
    k_agg<<<gAgg, 256, 0, stream>>>(zh, colb, es, ed, row_ptr, hb);

    // layers 2..8
    for (int l = 0; l < 7; ++l) {
        k_mfma<<<(NN + 127) / 128, 256, 0, stream>>>(hb, Wh + (size_t)l * NH * HF * HID,
                                                     vh + (size_t)l * 16 * HID, zh, es, ed);
        k_agg<<<gAgg, 256, 0, stream>>>(zh, colb, es, ed, row_ptr, hb);
    }

    k_fc<<<(NN + 3) / 4, 256, 0, stream>>>(hb, fcW, fcb, out);
}

// Round 12
// 1389.596 us; speedup vs baseline: 1.1013x; 1.0260x over previous
//
#include <hip/hip_runtime.h>
#include <hip/hip_bf16.h>
#include <hip/hip_fp16.h>
#include <math.h>

#define NN 100000
#define NE 1600000
#define INF_ 16
#define HF 64
#define NH 3
#define HID 192
#define NC 6
#define NEG_SLOPE 0.01f

#define BSH 9                 // bucket = dst >> 9 (512 nodes/bucket)
#define NBUCK 196             // ceil(100000/512)
#define TILE 2048

typedef _Float16 half8 __attribute__((ext_vector_type(8)));
typedef float f32x4 __attribute__((ext_vector_type(4)));

// ---------------- CSR build (bucketed) ----------------

__global__ __launch_bounds__(256) void k_bhist(const int* __restrict__ dst, int* __restrict__ bcnt) {
    __shared__ int c[NBUCK];
    int tid = threadIdx.x;
    for (int i = tid; i < NBUCK; i += 256) c[i] = 0;
    __syncthreads();
    int e0 = blockIdx.x * TILE;
    int end = min(e0 + TILE, NE);
    for (int i = e0 + tid; i < end; i += 256) atomicAdd(&c[dst[i] >> BSH], 1);
    __syncthreads();
    for (int i = tid; i < NBUCK; i += 256)
        if (c[i]) atomicAdd(&bcnt[i], c[i]);
}

__global__ __launch_bounds__(256) void k_bscan(const int* __restrict__ bcnt, int* __restrict__ bbase,
                                               int* __restrict__ gcur) {
    __shared__ int sc[256];
    int t = threadIdx.x;
    int v = (t < NBUCK) ? bcnt[t] : 0;
    sc[t] = v; __syncthreads();
    for (int off = 1; off < 256; off <<= 1) {
        int x = (t >= off) ? sc[t - off] : 0;
        __syncthreads();
        sc[t] += x;
        __syncthreads();
    }
    if (t < NBUCK) {
        bbase[t] = sc[t] - v;
        gcur[t] = sc[t] - v;
    }
    if (t == NBUCK - 1) bbase[NBUCK] = sc[t];   // == NE
}

__global__ __launch_bounds__(256) void k_bucket(const int* __restrict__ src, const int* __restrict__ dst,
                                                int* __restrict__ gcur, int* __restrict__ staged) {
    __shared__ int cnt[NBUCK], base[NBUCK], cnt2[NBUCK];
    int tid = threadIdx.x;
    int e0 = blockIdx.x * TILE;
    int cntE = min(TILE, NE - e0);
    for (int i = tid; i < NBUCK; i += 256) { cnt[i] = 0; cnt2[i] = 0; }
    __syncthreads();
    int myDst[8], mySrc[8];
#pragma unroll
    for (int k = 0; k < 8; ++k) {
        int idx = tid + k * 256;
        if (idx < cntE) {
            myDst[k] = dst[e0 + idx];
            mySrc[k] = src[e0 + idx];
            atomicAdd(&cnt[myDst[k] >> BSH], 1);
        }
    }
    __syncthreads();
    for (int i = tid; i < NBUCK; i += 256) {
        if (cnt[i] > 0) base[i] = atomicAdd(&gcur[i], cnt[i]);
    }
    __syncthreads();
#pragma unroll
    for (int k = 0; k < 8; ++k) {
        int idx = tid + k * 256;
        if (idx < cntE) {
            int b = myDst[k] >> BSH;
            int r = atomicAdd(&cnt2[b], 1);
            staged[base[b] + r] = ((myDst[k] & 511) << 17) | mySrc[k];
        }
    }
}

// pass B: per bucket: node hist + scan -> row_ptr slice; scatter colb; in-bucket
// degree counting-sort (descending) -> order[] (all LDS, ~free)
__global__ __launch_bounds__(256) void k_bscatter(const int* __restrict__ bbase, const int* __restrict__ staged,
                                                  int* __restrict__ colb, int* __restrict__ row_ptr,
                                                  int* __restrict__ order) {
    __shared__ int cnt[512];
    __shared__ int cur[512];
    __shared__ int ssum[256];
    __shared__ int dh2[256];
    int b = blockIdx.x;
    int tid = threadIdx.x;
    int beg = bbase[b];
    int end = bbase[b + 1];
    cnt[2 * tid] = 0; cnt[2 * tid + 1] = 0;
    dh2[tid] = 0;
    __syncthreads();
    for (int i = beg + tid; i < end; i += 256) atomicAdd(&cnt[staged[i] >> 17], 1);
    __syncthreads();
    int a0 = cnt[2 * tid], a1 = cnt[2 * tid + 1];
    int n0 = b << BSH;
    bool ok0 = (n0 + 2 * tid) < NN;
    bool ok1 = (n0 + 2 * tid + 1) < NN;
    ssum[tid] = a0 + a1;
    if (ok0) atomicAdd(&dh2[min(a0, 255)], 1);
    if (ok1) atomicAdd(&dh2[min(a1, 255)], 1);
    __syncthreads();
    for (int off = 1; off < 256; off <<= 1) {
        int x = (tid >= off) ? ssum[tid - off] : 0;
        __syncthreads();
        ssum[tid] += x;
        __syncthreads();
    }
    int ex = (tid ? ssum[tid - 1] : 0);
    int c0 = beg + ex;
    int c1 = beg + ex + a0;
    cur[2 * tid] = c0;
    cur[2 * tid + 1] = c1;
    if (ok0) row_ptr[n0 + 2 * tid] = c0;
    if (ok1) row_ptr[n0 + 2 * tid + 1] = c1;
    if (b == NBUCK - 1 && tid == 0) row_ptr[NN] = end;   // == NE
    __syncthreads();
    // descending-degree scan: thread t owns bin rb = 255-t
    int rb = 255 - tid;
    int dv = dh2[rb];
    ssum[tid] = dv;
    __syncthreads();
    for (int off = 1; off < 256; off <<= 1) {
        int x = (tid >= off) ? ssum[tid - off] : 0;
        __syncthreads();
        ssum[tid] += x;
        __syncthreads();
    }
    dh2[rb] = ssum[tid] - dv;   // exclusive rank base per bin
    __syncthreads();
    if (ok0) { int r = atomicAdd(&dh2[min(a0, 255)], 1); order[n0 + r] = n0 + 2 * tid; }
    if (ok1) { int r = atomicAdd(&dh2[min(a1, 255)], 1); order[n0 + r] = n0 + 2 * tid + 1; }
    __syncthreads();
    for (int i = beg + tid; i < end; i += 256) {
        int v = staged[i];
        int pos = atomicAdd(&cur[v >> 17], 1);
        colb[pos] = (v & 0x1FFFF) * 384;
    }
}

// ---------------- W fp32 -> fp16 ----------------

__global__ __launch_bounds__(256) void k_cvtW(const float* __restrict__ W, __half* __restrict__ Wh, int n) {
    int i = blockIdx.x * 256 + threadIdx.x;
    if (i < n) Wh[i] = __float2half(W[i]);
}

// ---------------- prep: v = W^T a per layer ----------------

__global__ __launch_bounds__(256) void k_prep(const float* __restrict__ W1, const float* __restrict__ a1,
                                              const float* __restrict__ W, const float* __restrict__ a,
                                              float* __restrict__ v0, __half* __restrict__ vh) {
    int bid = blockIdx.x, tid = threadIdx.x;
    if (bid == 0) {
        if (tid < 96) {
            int j = tid >> 4, k = tid & 15;
            int h = j % 3, sd = j / 3;
            float s = 0.f;
            for (int c = 0; c < 64; ++c)
                s += W1[h * 1024 + c * 16 + k] * a1[h * 128 + sd * 64 + c];
            v0[j * 16 + k] = s;
        }
    } else {
        int l = bid - 1;
        if (tid < HID) {
            int k = tid;
            __half* vt = vh + (size_t)l * 16 * HID;
            for (int j = 0; j < 6; ++j) {
                int h = j % 3, sd = j / 3;
                const float* wp = W + (size_t)l * 36864 + h * 12288 + k;
                const float* ap = a + (size_t)l * 384 + h * 128 + sd * 64;
                float s = 0.f;
                for (int c = 0; c < 64; ++c) s += wp[c * 192] * ap[c];
                __half hi = __float2half(s);
                __half lo = __float2half(s - __half2float(hi));
                vt[j * HID + k] = hi;
                vt[(j + 6) * HID + k] = lo;
            }
            for (int j = 12; j < 16; ++j) vt[j * HID + k] = __float2half(0.f);
        }
    }
}

// ---------------- layer 1 transform: thread = 4 nodes x 8 cols ----------------

__global__ __launch_bounds__(256) void k_transform1(const float* __restrict__ feat, const float* __restrict__ W1,
                                                    __half* __restrict__ zh) {
    int idx = blockIdx.x * 256 + threadIdx.x;
    if (idx >= (NN / 4) * 24) return;
    int n4 = idx / 24;
    int seg = idx - n4 * 24;      // 0..23: cols seg*8..+8
    int nbase = n4 * 4;
    const float* wr = W1 + seg * 8 * INF_;

    float acc[4][8];
#pragma unroll
    for (int j = 0; j < 4; ++j)
#pragma unroll
        for (int r = 0; r < 8; ++r) acc[j][r] = 0.f;

#pragma unroll
    for (int k4 = 0; k4 < 4; ++k4) {
        float4 f[4], w[8];
#pragma unroll
        for (int j = 0; j < 4; ++j) f[j] = *(const float4*)&feat[(nbase + j) * INF_ + k4 * 4];
#pragma unroll
        for (int r = 0; r < 8; ++r) w[r] = *(const float4*)&wr[r * INF_ + k4 * 4];
#pragma unroll
        for (int j = 0; j < 4; ++j)
#pragma unroll
            for (int r = 0; r < 8; ++r)
                acc[j][r] += f[j].x * w[r].x + f[j].y * w[r].y + f[j].z * w[r].z + f[j].w * w[r].w;
    }
#pragma unroll
    for (int j = 0; j < 4; ++j) {
        half8 o;
#pragma unroll
        for (int r = 0; r < 8; ++r) o[r] = (_Float16)acc[j][r];
        *(half8*)&zh[(size_t)(nbase + j) * HID + seg * 8] = o;
    }
}

// ---------------- layer 1 es/ed ----------------

__global__ __launch_bounds__(256) void k_esed1(const float* __restrict__ feat, const float* __restrict__ v0,
                                               float* __restrict__ es, float* __restrict__ ed) {
    __shared__ float sv[96];
    int tid = threadIdx.x;
    if (tid < 96) sv[tid] = v0[tid];
    __syncthreads();
    int n = blockIdx.x * 256 + tid;
    if (n >= NN) return;
    float f[16];
#pragma unroll
    for (int i = 0; i < 16; i += 4) {
        float4 t4 = *(const float4*)&feat[n * 16 + i];
        f[i] = t4.x; f[i + 1] = t4.y; f[i + 2] = t4.z; f[i + 3] = t4.w;
    }
#pragma unroll
    for (int j = 0; j < 6; ++j) {
        float s = 0.f;
#pragma unroll
        for (int k = 0; k < 16; ++k) s += f[k] * sv[j * 16 + k];
        if (j < 3) es[n * 3 + j] = s;
        else ed[n * 3 + (j - 3)] = s;
    }
}

// ---------------- layers 2..8 transform via MFMA, LDS-staged B (73.7KB), fused es/ed ----------------

__global__ __launch_bounds__(256) void k_mfma(const __half* __restrict__ Ah, const __half* __restrict__ Whl,
                                              const __half* __restrict__ vhl,
                                              __half* __restrict__ zh, float* __restrict__ es,
                                              float* __restrict__ ed) {
    __shared__ char Bs[73728];
    int tid = threadIdx.x;

#pragma unroll
    for (int i = 0; i < 18; ++i) {
        int idx = tid + i * 256;
        int row = idx / 24;
        int pos = idx - row * 24;
        uint4 v = *(const uint4*)((const char*)Whl + (size_t)idx * 16);
        *(uint4*)(Bs + row * 384 + ((pos * 16) ^ ((row & 7) << 4))) = v;
    }
    __syncthreads();

    int wid = tid >> 6;
    int lane = tid & 63;
    int lrow = lane & 15;
    int lk = lane >> 4;  // 0..3
    int r0 = blockIdx.x * 128 + wid * 32;

    int arow0 = min(r0 + lrow, NN - 1);
    int arow1 = min(r0 + 16 + lrow, NN - 1);
    const __half* ap0 = &Ah[(size_t)arow0 * HID];
    const __half* ap1 = &Ah[(size_t)arow1 * HID];

    f32x4 acc[2][12];
    f32x4 acc13[2];
#pragma unroll
    for (int f = 0; f < 2; ++f) {
        acc13[f] = (f32x4){0.f, 0.f, 0.f, 0.f};
#pragma unroll
        for (int t = 0; t < 12; ++t) acc[f][t] = (f32x4){0.f, 0.f, 0.f, 0.f};
    }

#pragma unroll
    for (int ks = 0; ks < 6; ++ks) {
        half8 a0 = *(const half8*)&ap0[ks * 32 + lk * 8];
        half8 a1 = *(const half8*)&ap1[ks * 32 + lk * 8];
        half8 b13 = *(const half8*)&vhl[lrow * HID + ks * 32 + lk * 8];
        acc13[0] = __builtin_amdgcn_mfma_f32_16x16x32_f16(a0, b13, acc13[0], 0, 0, 0);
        acc13[1] = __builtin_amdgcn_mfma_f32_16x16x32_f16(a1, b13, acc13[1], 0, 0, 0);
#pragma unroll
        for (int t = 0; t < 12; ++t) {
            int brow = t * 16 + lrow;
            half8 bf = *(const half8*)(Bs + brow * 384 + ((ks * 64 + lk * 16) ^ ((brow & 7) << 4)));
            acc[0][t] = __builtin_amdgcn_mfma_f32_16x16x32_f16(a0, bf, acc[0][t], 0, 0, 0);
            acc[1][t] = __builtin_amdgcn_mfma_f32_16x16x32_f16(a1, bf, acc[1][t], 0, 0, 0);
        }
    }

#pragma unroll
    for (int f = 0; f < 2; ++f) {
        int orow0 = r0 + f * 16 + lk * 4;
#pragma unroll
        for (int t = 0; t < 12; ++t) {
#pragma unroll
            for (int g = 0; g < 4; ++g) {
                int row = orow0 + g;
                if (row < NN) zh[(size_t)row * HID + t * 16 + lrow] = __float2half(acc[f][t][g]);
            }
        }
#pragma unroll
        for (int g = 0; g < 4; ++g) {
            float vhi = acc13[f][g];
            float vlo = __shfl(vhi, lane + 6);
            float tot = vhi + vlo;
            int row = orow0 + g;
            if (row < NN) {
                if (lrow < 3) es[row * NH + lrow] = tot;
                else if (lrow < 6) ed[row * NH + (lrow - 3)] = tot;
            }
        }
    }
}

// ---------------- aggregate: 8 node-slots x 8 lanes, unroll-2, order-balanced ----------------

__global__ __launch_bounds__(256) void k_agg(const __half* __restrict__ zh, const int* __restrict__ colb,
                                             const float* __restrict__ es, const float* __restrict__ ed,
                                             const int* __restrict__ row_ptr, const int* __restrict__ order,
                                             __half* __restrict__ h_out) {
    int w = blockIdx.x * 4 + (threadIdx.x >> 6);
    int slot = (threadIdx.x >> 3) & 7;
    int q = threadIdx.x & 7;
    int n = order[w * 8 + slot];   // equal-degree neighbors within wave
    int beg = row_ptr[n];
    int deg = row_ptr[n + 1] - beg;

    float3 d3 = *(const float3*)((const char*)ed + n * 12);

    float l0 = 0.f, l1 = 0.f, l2 = 0.f;
    float a0[8], a1[8], a2[8];
#pragma unroll
    for (int k = 0; k < 8; ++k) { a0[k] = 0.f; a1[k] = 0.f; a2[k] = 0.f; }

    const int* cp = colb + beg;
    const char* zb = (const char*)zh + q * 16;

    int soA = 0, soB = 0;
    float3 sA = make_float3(0.f, 0.f, 0.f), sB = sA;
    if (deg > 0) { soA = cp[0]; sA = *(const float3*)((const char*)es + (soA >> 5)); }
    if (deg > 1) { soB = cp[1]; sB = *(const float3*)((const char*)es + (soB >> 5)); }

    int i = 0;
    for (; i + 2 <= deg; i += 2) {
        const char* zpA = zb + soA;
        const char* zpB = zb + soB;
        half8 zA0 = *(const half8*)(zpA);
        half8 zA1 = *(const half8*)(zpA + 128);
        half8 zA2 = *(const half8*)(zpA + 256);
        half8 zB0 = *(const half8*)(zpB);
        half8 zB1 = *(const half8*)(zpB + 128);
        half8 zB2 = *(const half8*)(zpB + 256);
        float xA0 = sA.x + d3.x, xA1 = sA.y + d3.y, xA2 = sA.z + d3.z;
        float xB0 = sB.x + d3.x, xB1 = sB.y + d3.y, xB2 = sB.z + d3.z;
        xA0 = fmaxf(xA0, NEG_SLOPE * xA0); xA1 = fmaxf(xA1, NEG_SLOPE * xA1); xA2 = fmaxf(xA2, NEG_SLOPE * xA2);
        xB0 = fmaxf(xB0, NEG_SLOPE * xB0); xB1 = fmaxf(xB1, NEG_SLOPE * xB1); xB2 = fmaxf(xB2, NEG_SLOPE * xB2);
        float pA0 = __expf(xA0), pA1 = __expf(xA1), pA2 = __expf(xA2);
        float pB0 = __expf(xB0), pB1 = __expf(xB1), pB2 = __expf(xB2);
        if (i + 2 < deg) { soA = cp[i + 2]; sA = *(const float3*)((const char*)es + (soA >> 5)); }
        if (i + 3 < deg) { soB = cp[i + 3]; sB = *(const float3*)((const char*)es + (soB >> 5)); }
        l0 += pA0 + pB0; l1 += pA1 + pB1; l2 += pA2 + pB2;
#pragma unroll
        for (int k = 0; k < 8; ++k) {
            a0[k] += pA0 * (float)zA0[k] + pB0 * (float)zB0[k];
            a1[k] += pA1 * (float)zA1[k] + pB1 * (float)zB1[k];
            a2[k] += pA2 * (float)zA2[k] + pB2 * (float)zB2[k];
        }
    }
    if (i < deg) {
        const char* zpA = zb + soA;
        half8 zA0 = *(const half8*)(zpA);
        half8 zA1 = *(const half8*)(zpA + 128);
        half8 zA2 = *(const half8*)(zpA + 256);
        float xA0 = sA.x + d3.x, xA1 = sA.y + d3.y, xA2 = sA.z + d3.z;
        xA0 = fmaxf(xA0, NEG_SLOPE * xA0); xA1 = fmaxf(xA1, NEG_SLOPE * xA1); xA2 = fmaxf(xA2, NEG_SLOPE * xA2);
        float pA0 = __expf(xA0), pA1 = __expf(xA1), pA2 = __expf(xA2);
        l0 += pA0; l1 += pA1; l2 += pA2;
#pragma unroll
        for (int k = 0; k < 8; ++k) {
            a0[k] += pA0 * (float)zA0[k];
            a1[k] += pA1 * (float)zA1[k];
            a2[k] += pA2 * (float)zA2[k];
        }
    }

    float r0 = 1.f / fmaxf(l0, 1e-9f);
    float r1 = 1.f / fmaxf(l1, 1e-9f);
    float r2 = 1.f / fmaxf(l2, 1e-9f);
    char* ob = (char*)h_out + (size_t)n * 384 + q * 16;
    union { float4 f4; __half2 h2[4]; } u;
#pragma unroll
    for (int k = 0; k < 4; ++k) {
        float x0 = a0[2 * k] * r0, x1 = a0[2 * k + 1] * r0;
        x0 = (x0 > 0.f) ? x0 : (__expf(x0) - 1.f);
        x1 = (x1 > 0.f) ? x1 : (__expf(x1) - 1.f);
        u.h2[k] = __floats2half2_rn(x0, x1);
    }
    *(float4*)ob = u.f4;
#pragma unroll
    for (int k = 0; k < 4; ++k) {
        float x0 = a1[2 * k] * r1, x1 = a1[2 * k + 1] * r1;
        x0 = (x0 > 0.f) ? x0 : (__expf(x0) - 1.f);
        x1 = (x1 > 0.f) ? x1 : (__expf(x1) - 1.f);
        u.h2[k] = __floats2half2_rn(x0, x1);
    }
    *(float4*)(ob + 128) = u.f4;
#pragma unroll
    for (int k = 0; k < 4; ++k) {
        float x0 = a2[2 * k] * r2, x1 = a2[2 * k + 1] * r2;
        x0 = (x0 > 0.f) ? x0 : (__expf(x0) - 1.f);
        x1 = (x1 > 0.f) ? x1 : (__expf(x1) - 1.f);
        u.h2[k] = __floats2half2_rn(x0, x1);
    }
    *(float4*)(ob + 256) = u.f4;
}

// ---------------- final FC (fp16 h in) ----------------

__device__ inline float wred_sum(float v) {
#pragma unroll
    for (int o = 32; o; o >>= 1) v += __shfl_xor(v, o);
    return v;
}

__global__ __launch_bounds__(256) void k_fc(const __half* __restrict__ hbuf, const float* __restrict__ fcW,
                                            const float* __restrict__ fcb, float* __restrict__ out) {
    __shared__ float sW[NC * HID];
    __shared__ float sb[NC];
    int tid = threadIdx.x;
    for (int i = tid; i < NC * HID; i += 256) sW[i] = fcW[i];
    if (tid < NC) sb[tid] = fcb[tid];
    __syncthreads();
    int w = tid >> 6;
    int lane = tid & 63;
    int n = blockIdx.x * 4 + w;
    if (n >= NN) return;
    float h0 = __half2float(hbuf[(size_t)n * HID + lane]);
    float h1 = __half2float(hbuf[(size_t)n * HID + 64 + lane]);
    float h2 = __half2float(hbuf[(size_t)n * HID + 128 + lane]);
#pragma unroll
    for (int j = 0; j < NC; ++j) {
        float p = h0 * sW[j * HID + lane] + h1 * sW[j * HID + 64 + lane] + h2 * sW[j * HID + 128 + lane];
        p = wred_sum(p);
        if (lane == 0) out[n * NC + j] = p + sb[j];
    }
}

// ---------------- host ----------------

extern "C" void kernel_launch(void* const* d_in, const int* in_sizes, int n_in,
                              void* d_out, int out_size, void* d_ws, size_t ws_size,
                              hipStream_t stream) {
    const float* node_feat = (const float*)d_in[0];
    const int* src = (const int*)d_in[1];
    const int* dst = (const int*)d_in[2];
    const float* W1 = (const float*)d_in[3];   // [3,64,16]
    const float* a1 = (const float*)d_in[4];   // [3,128]
    const float* W = (const float*)d_in[5];    // [7,3,64,192]
    const float* a = (const float*)d_in[6];    // [7,3,128]
    const float* fcW = (const float*)d_in[7];  // [6,192]
    const float* fcb = (const float*)d_in[8];  // [6]
    float* out = (float*)d_out;

    char* p = (char*)d_ws;
    auto alloc = [&](size_t bytes) {
        void* r = (void*)p;
        p += (bytes + 255) & ~(size_t)255;
        return r;
    };
    int* row_ptr = (int*)alloc((NN + 1) * 4);
    int* bcnt = (int*)alloc(NBUCK * 4);
    int* bbase = (int*)alloc((NBUCK + 1) * 4);
    int* gcur = (int*)alloc(NBUCK * 4);
    int* order = (int*)alloc((size_t)NN * 4);
    int* staged = (int*)alloc((size_t)NE * 4);
    int* colb = (int*)alloc((size_t)NE * 4);
    float* es = (float*)alloc((size_t)NN * NH * 4);
    float* ed = (float*)alloc((size_t)NN * NH * 4);
    __half* zh = (__half*)alloc((size_t)NN * HID * 2);
    __half* hb = (__half*)alloc((size_t)NN * HID * 2);
    const int NWH = 7 * NH * HF * HID;  // 258048
    __half* Wh = (__half*)alloc((size_t)NWH * 2);
    float* v0 = (float*)alloc(96 * 4);
    __half* vh = (__half*)alloc((size_t)7 * 16 * HID * 2);

    int nb = (NN + 255) / 256;          // 391
    int gTile = (NE + TILE - 1) / TILE; // 782

    hipMemsetAsync(bcnt, 0, NBUCK * 4, stream);
    k_bhist<<<gTile, 256, 0, stream>>>(dst, bcnt);
    k_bscan<<<1, 256, 0, stream>>>(bcnt, bbase, gcur);
    k_bucket<<<gTile, 256, 0, stream>>>(src, dst, gcur, staged);
    k_bscatter<<<NBUCK, 256, 0, stream>>>(bbase, staged, colb, row_ptr, order);
    k_cvtW<<<(NWH + 255) / 256, 256, 0, stream>>>(W, Wh, NWH);
    k_prep<<<8, 256, 0, stream>>>(W1, a1, W, a, v0, vh);

    int gAgg = NN / 8 / 4;              // 3125 blocks, exact
    int gT1 = ((NN / 4) * 24 + 255) / 256;  // 2344

    // layer 1
    k_transform1<<<gT1, 256, 0, stream>>>(node_feat, W1, zh);
    k_esed1<<<nb, 256, 0, stream>>>(node_feat, v0, es, ed);
    k_agg<<<gAgg, 256, 0, stream>>>(zh, colb, es, ed, row_ptr, order, hb);

    // layers 2..8
    for (int l = 0; l < 7; ++l) {
        k_mfma<<<(NN + 127) / 128, 256, 0, stream>>>(hb, Wh + (size_t)l * NH * HF * HID,
                                                     vh + (size_t)l * 16 * HID, zh, es, ed);
        k_agg<<<gAgg, 256, 0, stream>>>(zh, colb, es, ed, row_ptr, order, hb);
    }

    k_fc<<<(NN + 3) / 4, 256, 0, stream>>>(hb, fcW, fcb, out);
}

// Round 13
// 1193.373 us; speedup vs baseline: 1.2823x; 1.1644x over previous
//
#include <hip/hip_runtime.h>
#include <hip/hip_bf16.h>
#include <hip/hip_fp16.h>
#include <math.h>

#define NN 100000
#define NE 1600000
#define INF_ 16
#define HF 64
#define NH 3
#define HID 192
#define NC 6
#define NEG_SLOPE 0.01f

#define BSH 9                 // bucket = dst >> 9 (512 nodes/bucket)
#define NBUCK 196             // ceil(100000/512)
#define TILE 2048

typedef _Float16 half8 __attribute__((ext_vector_type(8)));
typedef float f32x4 __attribute__((ext_vector_type(4)));

// ---------------- CSR build (bucketed) ----------------

__global__ __launch_bounds__(256) void k_bhist(const int* __restrict__ dst, int* __restrict__ bcnt) {
    __shared__ int c[NBUCK];
    int tid = threadIdx.x;
    for (int i = tid; i < NBUCK; i += 256) c[i] = 0;
    __syncthreads();
    int e0 = blockIdx.x * TILE;
    int end = min(e0 + TILE, NE);
    for (int i = e0 + tid; i < end; i += 256) atomicAdd(&c[dst[i] >> BSH], 1);
    __syncthreads();
    for (int i = tid; i < NBUCK; i += 256)
        if (c[i]) atomicAdd(&bcnt[i], c[i]);
}

__global__ __launch_bounds__(256) void k_bscan(const int* __restrict__ bcnt, int* __restrict__ bbase,
                                               int* __restrict__ gcur) {
    __shared__ int sc[256];
    int t = threadIdx.x;
    int v = (t < NBUCK) ? bcnt[t] : 0;
    sc[t] = v; __syncthreads();
    for (int off = 1; off < 256; off <<= 1) {
        int x = (t >= off) ? sc[t - off] : 0;
        __syncthreads();
        sc[t] += x;
        __syncthreads();
    }
    if (t < NBUCK) {
        bbase[t] = sc[t] - v;
        gcur[t] = sc[t] - v;
    }
    if (t == NBUCK - 1) bbase[NBUCK] = sc[t];   // == NE
}

__global__ __launch_bounds__(256) void k_bucket(const int* __restrict__ src, const int* __restrict__ dst,
                                                int* __restrict__ gcur, int* __restrict__ staged) {
    __shared__ int cnt[NBUCK], base[NBUCK], cnt2[NBUCK];
    int tid = threadIdx.x;
    int e0 = blockIdx.x * TILE;
    int cntE = min(TILE, NE - e0);
    for (int i = tid; i < NBUCK; i += 256) { cnt[i] = 0; cnt2[i] = 0; }
    __syncthreads();
    int myDst[8], mySrc[8];
#pragma unroll
    for (int k = 0; k < 8; ++k) {
        int idx = tid + k * 256;
        if (idx < cntE) {
            myDst[k] = dst[e0 + idx];
            mySrc[k] = src[e0 + idx];
            atomicAdd(&cnt[myDst[k] >> BSH], 1);
        }
    }
    __syncthreads();
    for (int i = tid; i < NBUCK; i += 256) {
        if (cnt[i] > 0) base[i] = atomicAdd(&gcur[i], cnt[i]);
    }
    __syncthreads();
#pragma unroll
    for (int k = 0; k < 8; ++k) {
        int idx = tid + k * 256;
        if (idx < cntE) {
            int b = myDst[k] >> BSH;
            int r = atomicAdd(&cnt2[b], 1);
            staged[base[b] + r] = ((myDst[k] & 511) << 17) | mySrc[k];
        }
    }
}

__global__ __launch_bounds__(256) void k_bscatter(const int* __restrict__ bbase, const int* __restrict__ staged,
                                                  int* __restrict__ colb, int* __restrict__ row_ptr) {
    __shared__ int cnt[512];
    __shared__ int cur[512];
    __shared__ int ssum[256];
    int b = blockIdx.x;
    int tid = threadIdx.x;
    int beg = bbase[b];
    int end = bbase[b + 1];
    cnt[2 * tid] = 0; cnt[2 * tid + 1] = 0;
    __syncthreads();
    for (int i = beg + tid; i < end; i += 256) atomicAdd(&cnt[staged[i] >> 17], 1);
    __syncthreads();
    int a0 = cnt[2 * tid], a1 = cnt[2 * tid + 1];
    ssum[tid] = a0 + a1;
    __syncthreads();
    for (int off = 1; off < 256; off <<= 1) {
        int x = (tid >= off) ? ssum[tid - off] : 0;
        __syncthreads();
        ssum[tid] += x;
        __syncthreads();
    }
    int ex = (tid ? ssum[tid - 1] : 0);
    int c0 = beg + ex;
    int c1 = beg + ex + a0;
    cur[2 * tid] = c0;
    cur[2 * tid + 1] = c1;
    int n0 = b << BSH;
    if (n0 + 2 * tid < NN) row_ptr[n0 + 2 * tid] = c0;
    if (n0 + 2 * tid + 1 < NN) row_ptr[n0 + 2 * tid + 1] = c1;
    if (b == NBUCK - 1 && tid == 0) row_ptr[NN] = end;   // == NE
    __syncthreads();
    for (int i = beg + tid; i < end; i += 256) {
        int v = staged[i];
        int pos = atomicAdd(&cur[v >> 17], 1);
        colb[pos] = (v & 0x1FFFF) * 384;
    }
}

// ---------------- W fp32 -> fp16 ----------------

__global__ __launch_bounds__(256) void k_cvtW(const float* __restrict__ W, __half* __restrict__ Wh, int n) {
    int i = blockIdx.x * 256 + threadIdx.x;
    if (i < n) Wh[i] = __float2half(W[i]);
}

// ---------------- prep: v = W^T a per layer ----------------

__global__ __launch_bounds__(256) void k_prep(const float* __restrict__ W1, const float* __restrict__ a1,
                                              const float* __restrict__ W, const float* __restrict__ a,
                                              float* __restrict__ v0, __half* __restrict__ vh) {
    int bid = blockIdx.x, tid = threadIdx.x;
    if (bid == 0) {
        if (tid < 96) {
            int j = tid >> 4, k = tid & 15;
            int h = j % 3, sd = j / 3;
            float s = 0.f;
            for (int c = 0; c < 64; ++c)
                s += W1[h * 1024 + c * 16 + k] * a1[h * 128 + sd * 64 + c];
            v0[j * 16 + k] = s;
        }
    } else {
        int l = bid - 1;
        if (tid < HID) {
            int k = tid;
            __half* vt = vh + (size_t)l * 16 * HID;
            for (int j = 0; j < 6; ++j) {
                int h = j % 3, sd = j / 3;
                const float* wp = W + (size_t)l * 36864 + h * 12288 + k;
                const float* ap = a + (size_t)l * 384 + h * 128 + sd * 64;
                float s = 0.f;
                for (int c = 0; c < 64; ++c) s += wp[c * 192] * ap[c];
                __half hi = __float2half(s);
                __half lo = __float2half(s - __half2float(hi));
                vt[j * HID + k] = hi;
                vt[(j + 6) * HID + k] = lo;
            }
            for (int j = 12; j < 16; ++j) vt[j * HID + k] = __float2half(0.f);
        }
    }
}

// ---------------- layer 1 transform: thread = 4 nodes x 8 cols ----------------

__global__ __launch_bounds__(256) void k_transform1(const float* __restrict__ feat, const float* __restrict__ W1,
                                                    __half* __restrict__ zh) {
    int idx = blockIdx.x * 256 + threadIdx.x;
    if (idx >= (NN / 4) * 24) return;
    int n4 = idx / 24;
    int seg = idx - n4 * 24;      // 0..23: cols seg*8..+8
    int nbase = n4 * 4;
    const float* wr = W1 + seg * 8 * INF_;

    float acc[4][8];
#pragma unroll
    for (int j = 0; j < 4; ++j)
#pragma unroll
        for (int r = 0; r < 8; ++r) acc[j][r] = 0.f;

#pragma unroll
    for (int k4 = 0; k4 < 4; ++k4) {
        float4 f[4], w[8];
#pragma unroll
        for (int j = 0; j < 4; ++j) f[j] = *(const float4*)&feat[(nbase + j) * INF_ + k4 * 4];
#pragma unroll
        for (int r = 0; r < 8; ++r) w[r] = *(const float4*)&wr[r * INF_ + k4 * 4];
#pragma unroll
        for (int j = 0; j < 4; ++j)
#pragma unroll
            for (int r = 0; r < 8; ++r)
                acc[j][r] += f[j].x * w[r].x + f[j].y * w[r].y + f[j].z * w[r].z + f[j].w * w[r].w;
    }
#pragma unroll
    for (int j = 0; j < 4; ++j) {
        half8 o;
#pragma unroll
        for (int r = 0; r < 8; ++r) o[r] = (_Float16)acc[j][r];
        *(half8*)&zh[(size_t)(nbase + j) * HID + seg * 8] = o;
    }
}

// ---------------- layer 1 es/ed ----------------

__global__ __launch_bounds__(256) void k_esed1(const float* __restrict__ feat, const float* __restrict__ v0,
                                               float* __restrict__ es, float* __restrict__ ed) {
    __shared__ float sv[96];
    int tid = threadIdx.x;
    if (tid < 96) sv[tid] = v0[tid];
    __syncthreads();
    int n = blockIdx.x * 256 + tid;
    if (n >= NN) return;
    float f[16];
#pragma unroll
    for (int i = 0; i < 16; i += 4) {
        float4 t4 = *(const float4*)&feat[n * 16 + i];
        f[i] = t4.x; f[i + 1] = t4.y; f[i + 2] = t4.z; f[i + 3] = t4.w;
    }
#pragma unroll
    for (int j = 0; j < 6; ++j) {
        float s = 0.f;
#pragma unroll
        for (int k = 0; k < 16; ++k) s += f[k] * sv[j * 16 + k];
        if (j < 3) es[n * 3 + j] = s;
        else ed[n * 3 + (j - 3)] = s;
    }
}

// ---------------- layers 2..8 transform via MFMA, LDS-staged B, reg-preloaded A/b13,
//                  LDS-transposed coalesced z store ----------------

__global__ __launch_bounds__(256) void k_mfma(const __half* __restrict__ Ah, const __half* __restrict__ Whl,
                                              const __half* __restrict__ vhl,
                                              __half* __restrict__ zh, float* __restrict__ es,
                                              float* __restrict__ ed) {
    __shared__ char Bs[73728];
    int tid = threadIdx.x;

    // stage B (192x192 fp16) with XOR-16B swizzle
#pragma unroll
    for (int i = 0; i < 18; ++i) {
        int idx = tid + i * 256;
        int row = idx / 24;
        int pos = idx - row * 24;
        uint4 v = *(const uint4*)((const char*)Whl + (size_t)idx * 16);
        *(uint4*)(Bs + row * 384 + ((pos * 16) ^ ((row & 7) << 4))) = v;
    }

    int wid = tid >> 6;
    int lane = tid & 63;
    int lrow = lane & 15;
    int lk = lane >> 4;  // 0..3
    int r0 = blockIdx.x * 128 + wid * 32;

    int arow0 = min(r0 + lrow, NN - 1);
    int arow1 = min(r0 + 16 + lrow, NN - 1);
    const __half* ap0 = &Ah[(size_t)arow0 * HID];
    const __half* ap1 = &Ah[(size_t)arow1 * HID];

    // preload A fragments + b13 columns to registers (overlaps with LDS staging)
    half8 a0r[6], a1r[6], b13r[6];
#pragma unroll
    for (int ks = 0; ks < 6; ++ks) {
        a0r[ks] = *(const half8*)&ap0[ks * 32 + lk * 8];
        a1r[ks] = *(const half8*)&ap1[ks * 32 + lk * 8];
        b13r[ks] = *(const half8*)&vhl[lrow * HID + ks * 32 + lk * 8];
    }

    f32x4 acc[2][12];
    f32x4 acc13[2];
#pragma unroll
    for (int f = 0; f < 2; ++f) {
        acc13[f] = (f32x4){0.f, 0.f, 0.f, 0.f};
#pragma unroll
        for (int t = 0; t < 12; ++t) acc[f][t] = (f32x4){0.f, 0.f, 0.f, 0.f};
    }

    __syncthreads();

#pragma unroll
    for (int ks = 0; ks < 6; ++ks) {
        acc13[0] = __builtin_amdgcn_mfma_f32_16x16x32_f16(a0r[ks], b13r[ks], acc13[0], 0, 0, 0);
        acc13[1] = __builtin_amdgcn_mfma_f32_16x16x32_f16(a1r[ks], b13r[ks], acc13[1], 0, 0, 0);
#pragma unroll
        for (int t = 0; t < 12; ++t) {
            int brow = t * 16 + lrow;
            half8 bf = *(const half8*)(Bs + brow * 384 + ((ks * 64 + lk * 16) ^ ((brow & 7) << 4)));
            acc[0][t] = __builtin_amdgcn_mfma_f32_16x16x32_f16(a0r[ks], bf, acc[0][t], 0, 0, 0);
            acc[1][t] = __builtin_amdgcn_mfma_f32_16x16x32_f16(a1r[ks], bf, acc[1][t], 0, 0, 0);
        }
    }

    // es/ed from acc13 (register-only + shfl)
#pragma unroll
    for (int f = 0; f < 2; ++f) {
        int orow0 = r0 + f * 16 + lk * 4;
#pragma unroll
        for (int g = 0; g < 4; ++g) {
            float vhi = acc13[f][g];
            float vlo = __shfl(vhi, lane + 6);
            float tot = vhi + vlo;
            int row = orow0 + g;
            if (row < NN) {
                if (lrow < 3) es[row * NH + lrow] = tot;
                else if (lrow < 6) ed[row * NH + (lrow - 3)] = tot;
            }
        }
    }

    // z store: transpose through LDS (reuse Bs), then coalesced 16B stores
    __syncthreads();   // all waves done reading Bs
#pragma unroll
    for (int f = 0; f < 2; ++f) {
#pragma unroll
        for (int t = 0; t < 12; ++t) {
#pragma unroll
            for (int g = 0; g < 4; ++g) {
                int lr = wid * 32 + f * 16 + lk * 4 + g;     // local row 0..127
                *(__half*)(Bs + lr * 384 + (t * 16 + lrow) * 2) = __float2half(acc[f][t][g]);
            }
        }
    }
    __syncthreads();
    int rbase = blockIdx.x * 128;
#pragma unroll
    for (int i = 0; i < 12; ++i) {
        int idx = tid + i * 256;                 // 0..3071
        int row = idx / 24;
        int pos = idx - row * 24;
        int grow = rbase + row;
        if (grow < NN)
            *(uint4*)((char*)zh + (size_t)grow * 384 + pos * 16) = *(const uint4*)(Bs + idx * 16);
    }
}

// ---------------- aggregate: 8 node-slots x 8 lanes, unroll-2 (R9-proven) ----------------

__global__ __launch_bounds__(256) void k_agg(const __half* __restrict__ zh, const int* __restrict__ colb,
                                             const float* __restrict__ es, const float* __restrict__ ed,
                                             const int* __restrict__ row_ptr, __half* __restrict__ h_out) {
    int w = blockIdx.x * 4 + (threadIdx.x >> 6);
    int slot = (threadIdx.x >> 3) & 7;
    int q = threadIdx.x & 7;
    int n = w * 8 + slot;          // identity order (locality-preserving)
    int beg = row_ptr[n];
    int deg = row_ptr[n + 1] - beg;

    float3 d3 = *(const float3*)((const char*)ed + n * 12);

    float l0 = 0.f, l1 = 0.f, l2 = 0.f;
    float a0[8], a1[8], a2[8];
#pragma unroll
    for (int k = 0; k < 8; ++k) { a0[k] = 0.f; a1[k] = 0.f; a2[k] = 0.f; }

    const int* cp = colb + beg;
    const char* zb = (const char*)zh + q * 16;

    int soA = 0, soB = 0;
    float3 sA = make_float3(0.f, 0.f, 0.f), sB = sA;
    if (deg > 0) { soA = cp[0]; sA = *(const float3*)((const char*)es + (soA >> 5)); }
    if (deg > 1) { soB = cp[1]; sB = *(const float3*)((const char*)es + (soB >> 5)); }

    int i = 0;
    for (; i + 2 <= deg; i += 2) {
        const char* zpA = zb + soA;
        const char* zpB = zb + soB;
        half8 zA0 = *(const half8*)(zpA);
        half8 zA1 = *(const half8*)(zpA + 128);
        half8 zA2 = *(const half8*)(zpA + 256);
        half8 zB0 = *(const half8*)(zpB);
        half8 zB1 = *(const half8*)(zpB + 128);
        half8 zB2 = *(const half8*)(zpB + 256);
        float xA0 = sA.x + d3.x, xA1 = sA.y + d3.y, xA2 = sA.z + d3.z;
        float xB0 = sB.x + d3.x, xB1 = sB.y + d3.y, xB2 = sB.z + d3.z;
        xA0 = fmaxf(xA0, NEG_SLOPE * xA0); xA1 = fmaxf(xA1, NEG_SLOPE * xA1); xA2 = fmaxf(xA2, NEG_SLOPE * xA2);
        xB0 = fmaxf(xB0, NEG_SLOPE * xB0); xB1 = fmaxf(xB1, NEG_SLOPE * xB1); xB2 = fmaxf(xB2, NEG_SLOPE * xB2);
        float pA0 = __expf(xA0), pA1 = __expf(xA1), pA2 = __expf(xA2);
        float pB0 = __expf(xB0), pB1 = __expf(xB1), pB2 = __expf(xB2);
        if (i + 2 < deg) { soA = cp[i + 2]; sA = *(const float3*)((const char*)es + (soA >> 5)); }
        if (i + 3 < deg) { soB = cp[i + 3]; sB = *(const float3*)((const char*)es + (soB >> 5)); }
        l0 += pA0 + pB0; l1 += pA1 + pB1; l2 += pA2 + pB2;
#pragma unroll
        for (int k = 0; k < 8; ++k) {
            a0[k] += pA0 * (float)zA0[k] + pB0 * (float)zB0[k];
            a1[k] += pA1 * (float)zA1[k] + pB1 * (float)zB1[k];
            a2[k] += pA2 * (float)zA2[k] + pB2 * (float)zB2[k];
        }
    }
    if (i < deg) {
        const char* zpA = zb + soA;
        half8 zA0 = *(const half8*)(zpA);
        half8 zA1 = *(const half8*)(zpA + 128);
        half8 zA2 = *(const half8*)(zpA + 256);
        float xA0 = sA.x + d3.x, xA1 = sA.y + d3.y, xA2 = sA.z + d3.z;
        xA0 = fmaxf(xA0, NEG_SLOPE * xA0); xA1 = fmaxf(xA1, NEG_SLOPE * xA1); xA2 = fmaxf(xA2, NEG_SLOPE * xA2);
        float pA0 = __expf(xA0), pA1 = __expf(xA1), pA2 = __expf(xA2);
        l0 += pA0; l1 += pA1; l2 += pA2;
#pragma unroll
        for (int k = 0; k < 8; ++k) {
            a0[k] += pA0 * (float)zA0[k];
            a1[k] += pA1 * (float)zA1[k];
            a2[k] += pA2 * (float)zA2[k];
        }
    }

    float r0 = 1.f / fmaxf(l0, 1e-9f);
    float r1 = 1.f / fmaxf(l1, 1e-9f);
    float r2 = 1.f / fmaxf(l2, 1e-9f);
    char* ob = (char*)h_out + (size_t)n * 384 + q * 16;
    union { float4 f4; __half2 h2[4]; } u;
#pragma unroll
    for (int k = 0; k < 4; ++k) {
        float x0 = a0[2 * k] * r0, x1 = a0[2 * k + 1] * r0;
        x0 = (x0 > 0.f) ? x0 : (__expf(x0) - 1.f);
        x1 = (x1 > 0.f) ? x1 : (__expf(x1) - 1.f);
        u.h2[k] = __floats2half2_rn(x0, x1);
    }
    *(float4*)ob = u.f4;
#pragma unroll
    for (int k = 0; k < 4; ++k) {
        float x0 = a1[2 * k] * r1, x1 = a1[2 * k + 1] * r1;
        x0 = (x0 > 0.f) ? x0 : (__expf(x0) - 1.f);
        x1 = (x1 > 0.f) ? x1 : (__expf(x1) - 1.f);
        u.h2[k] = __floats2half2_rn(x0, x1);
    }
    *(float4*)(ob + 128) = u.f4;
#pragma unroll
    for (int k = 0; k < 4; ++k) {
        float x0 = a2[2 * k] * r2, x1 = a2[2 * k + 1] * r2;
        x0 = (x0 > 0.f) ? x0 : (__expf(x0) - 1.f);
        x1 = (x1 > 0.f) ? x1 : (__expf(x1) - 1.f);
        u.h2[k] = __floats2half2_rn(x0, x1);
    }
    *(float4*)(ob + 256) = u.f4;
}

// ---------------- final FC (fp16 h in) ----------------

__device__ inline float wred_sum(float v) {
#pragma unroll
    for (int o = 32; o; o >>= 1) v += __shfl_xor(v, o);
    return v;
}

__global__ __launch_bounds__(256) void k_fc(const __half* __restrict__ hbuf, const float* __restrict__ fcW,
                                            const float* __restrict__ fcb, float* __restrict__ out) {
    __shared__ float sW[NC * HID];
    __shared__ float sb[NC];
    int tid = threadIdx.x;
    for (int i = tid; i < NC * HID; i += 256) sW[i] = fcW[i];
    if (tid < NC) sb[tid] = fcb[tid];
    __syncthreads();
    int w = tid >> 6;
    int lane = tid & 63;
    int n = blockIdx.x * 4 + w;
    if (n >= NN) return;
    float h0 = __half2float(hbuf[(size_t)n * HID + lane]);
    float h1 = __half2float(hbuf[(size_t)n * HID + 64 + lane]);
    float h2 = __half2float(hbuf[(size_t)n * HID + 128 + lane]);
#pragma unroll
    for (int j = 0; j < NC; ++j) {
        float p = h0 * sW[j * HID + lane] + h1 * sW[j * HID + 64 + lane] + h2 * sW[j * HID + 128 + lane];
        p = wred_sum(p);
        if (lane == 0) out[n * NC + j] = p + sb[j];
    }
}

// ---------------- host ----------------

extern "C" void kernel_launch(void* const* d_in, const int* in_sizes, int n_in,
                              void* d_out, int out_size, void* d_ws, size_t ws_size,
                              hipStream_t stream) {
    const float* node_feat = (const float*)d_in[0];
    const int* src = (const int*)d_in[1];
    const int* dst = (const int*)d_in[2];
    const float* W1 = (const float*)d_in[3];   // [3,64,16]
    const float* a1 = (const float*)d_in[4];   // [3,128]
    const float* W = (const float*)d_in[5];    // [7,3,64,192]
    const float* a = (const float*)d_in[6];    // [7,3,128]
    const float* fcW = (const float*)d_in[7];  // [6,192]
    const float* fcb = (const float*)d_in[8];  // [6]
    float* out = (float*)d_out;

    char* p = (char*)d_ws;
    auto alloc = [&](size_t bytes) {
        void* r = (void*)p;
        p += (bytes + 255) & ~(size_t)255;
        return r;
    };
    int* row_ptr = (int*)alloc((NN + 1) * 4);
    int* bcnt = (int*)alloc(NBUCK * 4);
    int* bbase = (int*)alloc((NBUCK + 1) * 4);
    int* gcur = (int*)alloc(NBUCK * 4);
    int* staged = (int*)alloc((size_t)NE * 4);
    int* colb = (int*)alloc((size_t)NE * 4);
    float* es = (float*)alloc((size_t)NN * NH * 4);
    float* ed = (float*)alloc((size_t)NN * NH * 4);
    __half* zh = (__half*)alloc((size_t)NN * HID * 2);
    __half* hb = (__half*)alloc((size_t)NN * HID * 2);
    const int NWH = 7 * NH * HF * HID;  // 258048
    __half* Wh = (__half*)alloc((size_t)NWH * 2);
    float* v0 = (float*)alloc(96 * 4);
    __half* vh = (__half*)alloc((size_t)7 * 16 * HID * 2);

    int nb = (NN + 255) / 256;          // 391
    int gTile = (NE + TILE - 1) / TILE; // 782

    hipMemsetAsync(bcnt, 0, NBUCK * 4, stream);
    k_bhist<<<gTile, 256, 0, stream>>>(dst, bcnt);
    k_bscan<<<1, 256, 0, stream>>>(bcnt, bbase, gcur);
    k_bucket<<<gTile, 256, 0, stream>>>(src, dst, gcur, staged);
    k_bscatter<<<NBUCK, 256, 0, stream>>>(bbase, staged, colb, row_ptr);
    k_cvtW<<<(NWH + 255) / 256, 256, 0, stream>>>(W, Wh, NWH);
    k_prep<<<8, 256, 0, stream>>>(W1, a1, W, a, v0, vh);

    int gAgg = NN / 8 / 4;              // 3125 blocks, exact
    int gT1 = ((NN / 4) * 24 + 255) / 256;  // 2344

    // layer 1
    k_transform1<<<gT1, 256, 0, stream>>>(node_feat, W1, zh);
    k_esed1<<<nb, 256, 0, stream>>>(node_feat, v0, es, ed);
    k_agg<<<gAgg, 256, 0, stream>>>(zh, colb, es, ed, row_ptr, hb);

    // layers 2..8
    for (int l = 0; l < 7; ++l) {
        k_mfma<<<(NN + 127) / 128, 256, 0, stream>>>(hb, Wh + (size_t)l * NH * HF * HID,
                                                     vh + (size_t)l * 16 * HID, zh, es, ed);
        k_agg<<<gAgg, 256, 0, stream>>>(zh, colb, es, ed, row_ptr, hb);
    }

    k_fc<<<(NN + 3) / 4, 256, 0, stream>>>(hb, fcW, fcb, out);
}